// Round 9
// baseline (199.765 us; speedup 1.0000x reference)
//
#include <hip/hip_runtime.h>
#include <cmath>

// Problem constants (LowRankExperts)
constexpr int kE = 16;
constexpr int kB = 1024;
constexpr int kI = 512;
constexpr int kH = 16;
constexpr int kF = 8192;           // I*R + R*O
constexpr int kAH = 4096;          // I*R (first half of f -> A)
constexpr long long kATOT = (long long)kE * kB * kAH;  // 67108864 floats in A

typedef float f32x4 __attribute__((ext_vector_type(4)));

// ---------------------------------------------------------------------------
// Kernel A: h[e*B+b][hh] = tanh(dot(x[b,:], W1[e,:,hh]) + b1[e][hh])
// grid: (B/16, E), block: 256 = 16 b-rows x 16 hh
// ---------------------------------------------------------------------------
__global__ __launch_bounds__(256) void k_hidden(const float* __restrict__ x,
                                                const float* __restrict__ W1,
                                                const float* __restrict__ b1,
                                                float* __restrict__ hws) {
  __shared__ float xs[16][520];
  const int e  = blockIdx.y;
  const int b0 = blockIdx.x * 16;
  const int tid = threadIdx.x;

  const float4* xg = (const float4*)(x + (size_t)b0 * kI);
#pragma unroll
  for (int k = 0; k < 8; ++k) {
    int idx = tid + k * 256;            // float4 index 0..2047
    float4 v = xg[idx];
    int row = idx >> 7;                 // 128 float4 per row
    int col = (idx & 127) << 2;
    *(float4*)&xs[row][col] = v;
  }
  __syncthreads();

  const int hh = tid & 15;
  const int bl = tid >> 4;
  const float* w1e = W1 + (size_t)e * kI * kH + hh;

  float acc = 0.f;
#pragma unroll 8
  for (int i = 0; i < kI; ++i) {
    acc = fmaf(xs[bl][i], w1e[i * kH], acc);
  }
  acc += b1[e * kH + hh];
  hws[(size_t)(e * kB + b0 + bl) * kH + hh] = tanhf(acc);
}

// ---------------------------------------------------------------------------
// Kernel B: R8 structure (scalar h via SGPRs, no LDS) with the store/load
// L2 policy INVERTED: plain f32x4 stores (the fill-proven 6.6TB/s write path
// through L2) + NON-TEMPORAL W2 loads (W2 bypasses L2 entirely -> the write
// stream has nothing to evict; W2 is served from the 256MB L3 where its 8MB
// working set is resident).
// grid: (B/32, F/1024, E), block: 256 threads = 256 distinct j-float4-cols.
// ---------------------------------------------------------------------------
__global__ __launch_bounds__(256) void k_factors(const float* __restrict__ hws,
                                                 const float* __restrict__ W2,
                                                 const float* __restrict__ b2,
                                                 float* __restrict__ out) {
  const int e  = blockIdx.z;
  const int b0 = blockIdx.x * 32;
  const int j0 = blockIdx.y * 1024;
  const int tid = threadIdx.x;

  const int j = j0 + tid * 4;     // this thread's 4 output columns

  // Load W2 column slice: 16 f32x4, register-resident, NT (L2-bypass).
  const float* w2ej = W2 + (size_t)e * kH * kF + j;
  f32x4 w[kH];
#pragma unroll
  for (int hh = 0; hh < kH; ++hh)
    w[hh] = __builtin_nontemporal_load((const f32x4*)(w2ej + hh * kF));

  const f32x4 bias = __builtin_nontemporal_load((const f32x4*)(b2 + (size_t)e * kF + j));

  // Destination base: A region or Bf region (tile never straddles: 1024|4096).
  float* dst;
  if (j0 < kAH) {
    dst = out + (size_t)(e * kB + b0) * (size_t)kAH + j;
  } else {
    dst = out + (size_t)kATOT + (size_t)(e * kB + b0) * (size_t)kAH + (j - kAH);
  }

  // h rows for this b-tile: block-uniform addresses -> scalar loads (SGPRs).
  const float* hbase = hws + (size_t)(e * kB + b0) * kH;

#pragma unroll 4
  for (int rr = 0; rr < 32; ++rr) {
    f32x4 acc = bias;
#pragma unroll
    for (int k = 0; k < kH; ++k) {
      const float hv = hbase[rr * kH + k];   // wave-uniform -> s_load
      acc.x = fmaf(hv, w[k].x, acc.x);
      acc.y = fmaf(hv, w[k].y, acc.y);
      acc.z = fmaf(hv, w[k].z, acc.z);
      acc.w = fmaf(hv, w[k].w, acc.w);
    }
    *(f32x4*)(dst + (size_t)rr * (size_t)kAH) = acc;   // plain store (L2 path)
  }
}

extern "C" void kernel_launch(void* const* d_in, const int* in_sizes, int n_in,
                              void* d_out, int out_size, void* d_ws, size_t ws_size,
                              hipStream_t stream) {
  const float* x  = (const float*)d_in[0];
  const float* W1 = (const float*)d_in[1];
  const float* b1 = (const float*)d_in[2];
  const float* W2 = (const float*)d_in[3];
  const float* b2 = (const float*)d_in[4];
  float* out = (float*)d_out;
  float* hws = (float*)d_ws;  // E*B*H floats = 1 MB

  k_hidden<<<dim3(kB / 16, kE), 256, 0, stream>>>(x, W1, b1, hws);
  k_factors<<<dim3(kB / 32, kF / 1024, kE), 256, 0, stream>>>(hws, W2, b2, out);
}

// Round 10
// 178.538 us; speedup vs baseline: 1.1189x; 1.1189x over previous
//
#include <hip/hip_runtime.h>
#include <cmath>

// Problem constants (LowRankExperts)
constexpr int kE = 16;
constexpr int kB = 1024;
constexpr int kI = 512;
constexpr int kH = 16;
constexpr int kF = 8192;           // I*R + R*O
constexpr int kAH = 4096;          // I*R (first half of f -> A)
constexpr long long kATOT = (long long)kE * kB * kAH;  // 67108864 floats in A

typedef float f32x4 __attribute__((ext_vector_type(4)));

// ---------------------------------------------------------------------------
// Kernel A: h[e*B+b][hh] = tanh(dot(x[b,:], W1[e,:,hh]) + b1[e][hh])
// grid: (B/16, E), block: 256 = 16 b-rows x 16 hh
// ---------------------------------------------------------------------------
__global__ __launch_bounds__(256) void k_hidden(const float* __restrict__ x,
                                                const float* __restrict__ W1,
                                                const float* __restrict__ b1,
                                                float* __restrict__ hws) {
  __shared__ float xs[16][520];
  const int e  = blockIdx.y;
  const int b0 = blockIdx.x * 16;
  const int tid = threadIdx.x;

  const float4* xg = (const float4*)(x + (size_t)b0 * kI);
#pragma unroll
  for (int k = 0; k < 8; ++k) {
    int idx = tid + k * 256;            // float4 index 0..2047
    float4 v = xg[idx];
    int row = idx >> 7;                 // 128 float4 per row
    int col = (idx & 127) << 2;
    *(float4*)&xs[row][col] = v;
  }
  __syncthreads();

  const int hh = tid & 15;
  const int bl = tid >> 4;
  const float* w1e = W1 + (size_t)e * kI * kH + hh;

  float acc = 0.f;
#pragma unroll 8
  for (int i = 0; i < kI; ++i) {
    acc = fmaf(xs[bl][i], w1e[i * kH], acc);
  }
  acc += b1[e * kH + hh];
  hws[(size_t)(e * kB + b0 + bl) * kH + hh] = tanhf(acc);
}

// ---------------------------------------------------------------------------
// Kernel B deep-sweep: block = (e, 1024-col j-tile, 128 b-rows).
// W2 slice (16 float4/thread) loaded into REGISTERS ONCE and held across all
// 128 rows -> W2 never depends on L2 reuse (total HBM W2 fetch <= 64MB, 8x
// fewer prologues than R2). h read via wave-uniform scalar loads (SGPR path,
// R8-proven). PLAIN stores: with zero read pressure on L2, this tests whether
// the plain-store path can reach the fill-proven 6.7 TB/s.
// grid: 1024 = E(16) x jt(8) x b8(8); block: 256 thr = 256 j-float4-cols.
// Decode: consecutive blocks share (e,jt) across b8 -> XCD-local W2 reuse.
// ---------------------------------------------------------------------------
__global__ __launch_bounds__(256) void k_factors(const float* __restrict__ hws,
                                                 const float* __restrict__ W2,
                                                 const float* __restrict__ b2,
                                                 float* __restrict__ out) {
  const int gid  = blockIdx.x;
  const int e    = gid >> 6;             // 64 blocks per expert
  const int loc  = gid & 63;
  const int jt   = loc >> 3;             // 8 j-tiles of 1024 cols
  const int b8   = loc & 7;              // 8 b-chunks of 128 rows
  const int tid  = threadIdx.x;

  const int j0 = jt * 1024;
  const int b0 = b8 * 128;
  const int j  = j0 + tid * 4;

  // W2 column slice: 16 float4, register-resident for the whole block.
  const float* w2ej = W2 + (size_t)e * kH * kF + j;
  float4 w[kH];
#pragma unroll
  for (int hh = 0; hh < kH; ++hh) w[hh] = *(const float4*)(w2ej + hh * kF);

  const float4 bias = *(const float4*)(b2 + (size_t)e * kF + j);

  // Destination base (tile never straddles the 4096 boundary).
  float* dst;
  if (j0 < kAH) {
    dst = out + (size_t)(e * kB + b0) * (size_t)kAH + j;
  } else {
    dst = out + (size_t)kATOT + (size_t)(e * kB + b0) * (size_t)kAH + (j - kAH);
  }

  // h rows: block-uniform addresses -> scalar loads (SGPRs).
  const float* hbase = hws + (size_t)(e * kB + b0) * kH;

#pragma unroll 4
  for (int rr = 0; rr < 128; ++rr) {
    float4 acc = bias;
#pragma unroll
    for (int k = 0; k < kH; ++k) {
      const float hv = hbase[rr * kH + k];   // wave-uniform -> s_load
      acc.x = fmaf(hv, w[k].x, acc.x);
      acc.y = fmaf(hv, w[k].y, acc.y);
      acc.z = fmaf(hv, w[k].z, acc.z);
      acc.w = fmaf(hv, w[k].w, acc.w);
    }
    f32x4 v; v.x = acc.x; v.y = acc.y; v.z = acc.z; v.w = acc.w;
    *(f32x4*)(dst + (size_t)rr * (size_t)kAH) = v;   // plain store (L2 is read-free)
  }
}

extern "C" void kernel_launch(void* const* d_in, const int* in_sizes, int n_in,
                              void* d_out, int out_size, void* d_ws, size_t ws_size,
                              hipStream_t stream) {
  const float* x  = (const float*)d_in[0];
  const float* W1 = (const float*)d_in[1];
  const float* b1 = (const float*)d_in[2];
  const float* W2 = (const float*)d_in[3];
  const float* b2 = (const float*)d_in[4];
  float* out = (float*)d_out;
  float* hws = (float*)d_ws;  // E*B*H floats = 1 MB

  k_hidden<<<dim3(kB / 16, kE), 256, 0, stream>>>(x, W1, b1, hws);
  k_factors<<<dim3(1024), 256, 0, stream>>>(hws, W2, b2, out);
}